// Round 6
// baseline (479.153 us; speedup 1.0000x reference)
//
#include <hip/hip_runtime.h>

// TBStars2 MoE sparse block — fp32 I/O, bf16 MFMA compute
// R14: minimum-sync "drift" K-loops in both GEMMs. Per K-tile only 2 barriers:
//  B1 (readers of the overwrite-target buffer done) -> issue 8 gld16 for t+1
//  -> counted vmcnt(8) (tile-t loads landed, t+1 stays in flight) -> B2
//  (everyone's tile-t slices landed) -> barrier-free ds_read+MFMA region so
//  waves drift and LDS reads overlap MFMA across waves (R13 analysis: LDS-read
//  time ~= MFMA time ~= 31us each, serialized by the old lockstep barriers).
//  gemm2 upgraded to 256x128 / 8 waves / dbuf (96KB LDS, vmcnt(6)).
// I/O structure from R13: cvt kernels, router zeroes out-rows, gemm2 atomicAdds.
#define T 4096
#define Hdim 1024
#define Fdim 2048
#define NE 8
#define TOPK 2
#define TK (T*TOPK)

typedef unsigned short ushort_t;
typedef __attribute__((ext_vector_type(8))) short bf16x8;   // 8 x bf16 (4 VGPRs)
typedef __attribute__((ext_vector_type(4))) float floatx4;  // mfma accumulator

__device__ __forceinline__ ushort_t f2bf(float f) {
    unsigned u = __float_as_uint(f);
    u += 0x7fff + ((u >> 16) & 1);   // RNE
    return (ushort_t)(u >> 16);
}
__device__ __forceinline__ uint4 cvt8(const float4 a, const float4 b) {
    uint4 r;
    r.x = (unsigned)f2bf(a.x) | ((unsigned)f2bf(a.y) << 16);
    r.y = (unsigned)f2bf(a.z) | ((unsigned)f2bf(a.w) << 16);
    r.z = (unsigned)f2bf(b.x) | ((unsigned)f2bf(b.y) << 16);
    r.w = (unsigned)f2bf(b.z) | ((unsigned)f2bf(b.w) << 16);
    return r;
}
// async 16B global->LDS (per-lane gather src; LDS dest = wave base + lane*16)
__device__ __forceinline__ void gld16(const ushort_t* g, short* l) {
    __builtin_amdgcn_global_load_lds((const __attribute__((address_space(1))) void*)g,
                                     (__attribute__((address_space(3))) void*)l, 16, 0, 0);
}

// ---------------------------------------------------------------------------
// K0: fp32 -> bf16 convert, exact grid, 8 elems/thread
__global__ __launch_bounds__(256) void cvt_kernel(const float* __restrict__ src,
                                                  ushort_t* __restrict__ dst)
{
    long i = (long)blockIdx.x * 256 + threadIdx.x;
    float4 a = *(const float4*)(src + i * 8);
    float4 b = *(const float4*)(src + i * 8 + 4);
    *(uint4*)(dst + i * 8) = cvt8(a, b);
}

// ---------------------------------------------------------------------------
// K1: router. One wave per token, fp32. Also converts its hs row -> hsb (bf16),
// zeroes its out row (gemm2 accumulates into it atomically), and (block 0)
// zeroes counts.
__global__ __launch_bounds__(64) void router_kernel(
    const float* __restrict__ hs, const float* __restrict__ gw,
    float* __restrict__ logits_out, float* __restrict__ out,
    ushort_t* __restrict__ hsb,
    int2* __restrict__ choice, float2* __restrict__ cwt, int* __restrict__ counts)
{
    const int t = blockIdx.x;
    const int lane = threadIdx.x;
    if (t == 0 && lane < NE) counts[lane] = 0;

    float hreg[16];
#pragma unroll
    for (int i = 0; i < 16; ++i)
        hreg[i] = hs[(long)t * Hdim + lane + 64 * i];

#pragma unroll
    for (int i = 0; i < 16; ++i)
        hsb[(long)t * Hdim + lane + 64 * i] = f2bf(hreg[i]);

    // zero this token's output row (accumulated by gemm2 atomics)
    const float4 z4 = make_float4(0.f, 0.f, 0.f, 0.f);
#pragma unroll
    for (int i = 0; i < 4; ++i)
        *(float4*)&out[(long)t * Hdim + lane * 4 + 256 * i] = z4;

    float acc[NE];
#pragma unroll
    for (int e = 0; e < NE; ++e) {
        float s = 0.f;
#pragma unroll
        for (int i = 0; i < 16; ++i)
            s += hreg[i] * gw[e * Hdim + lane + 64 * i];
#pragma unroll
        for (int off = 32; off > 0; off >>= 1)
            s += __shfl_xor(s, off, 64);
        acc[e] = s;
    }

    if (lane < NE) logits_out[t * NE + lane] = acc[lane];

    if (lane == 0) {
        int i1 = 0;
#pragma unroll
        for (int e = 1; e < NE; ++e) if (acc[e] > acc[i1]) i1 = e;
        int i2 = -1;
#pragma unroll
        for (int e = 0; e < NE; ++e) {
            if (e == i1) continue;
            if (i2 < 0 || acc[e] > acc[i2]) i2 = e;
        }
        float p2 = __expf(acc[i2] - acc[i1]);
        float z  = 1.f + p2;
        choice[t] = make_int2(i1, i2);
        cwt[t]    = make_float2(1.f / z, p2 / z);
    }
}

// K1b: scatter. Block = 256 tokens. LDS histogram -> 8 global atomics/block.
__global__ __launch_bounds__(256) void scatter_kernel(
    const int2* __restrict__ choice, const float2* __restrict__ cwt,
    int* __restrict__ counts, int* __restrict__ tok_slot, float* __restrict__ tok_wt)
{
    __shared__ int lhist[NE];
    __shared__ int lbase[NE];
    __shared__ int lpos[NE];
    const int tid = threadIdx.x;
    if (tid < NE) { lhist[tid] = 0; lpos[tid] = 0; }
    __syncthreads();

    const int t = blockIdx.x * 256 + tid;
    int2   ch = choice[t];
    float2 wv = cwt[t];
    atomicAdd(&lhist[ch.x], 1);
    atomicAdd(&lhist[ch.y], 1);
    __syncthreads();

    if (tid < NE) lbase[tid] = atomicAdd(&counts[tid], lhist[tid]);
    __syncthreads();

    int p1 = atomicAdd(&lpos[ch.x], 1);   // ch.x != ch.y
    int p2 = atomicAdd(&lpos[ch.y], 1);
    int o1 = lbase[ch.x] + p1;
    int o2 = lbase[ch.y] + p2;
    tok_slot[ch.x * T + o1] = t * TOPK + 0;
    tok_wt [ch.x * T + o1] = wv.x;
    tok_slot[ch.y * T + o2] = t * TOPK + 1;
    tok_wt [ch.y * T + o2] = wv.y;
}

// ---------------------------------------------------------------------------
// K2: gather-GEMM1 + SwiGLU. 256 slots x 128 f (B rows: 128 gate + 128 up),
// 512 threads = 8 waves (4m x 2fn), BK=64, 16 K-tiles, double-buffered LDS
// (128 KB), 2-barrier drift loop with counted vmcnt(8).
__global__ __launch_bounds__(512) void gemm1_kernel(
    const ushort_t* __restrict__ hsb, const ushort_t* __restrict__ w1b,
    const int* __restrict__ counts, const int* __restrict__ tok_slot,
    ushort_t* __restrict__ actb)
{
    const int e = blockIdx.z;
    const int cnt = counts[e];
    const int row0 = blockIdx.y * 256;
    if (row0 >= cnt) return;
    const int f0 = blockIdx.x * 128;

    __shared__ short As[2][256 * 64];    // 2 x 32 KB
    __shared__ short Bs[2][256 * 64];    // 2 x 32 KB: rows 0-127 gate, 128-255 up
    __shared__ int slotLds[256];

    const int tid = threadIdx.x;
    if (tid < 256) {
        int idx = row0 + tid;
        slotLds[tid] = (idx < cnt) ? tok_slot[e * T + idx] : -1;
    }
    __syncthreads();

    // staging pointers: 4 A-chunks + 4 B-chunks per thread (2048 chunks each)
    const ushort_t* srcA[4];
    const ushort_t* srcB[4];
#pragma unroll
    for (int i = 0; i < 4; ++i) {
        int ci = i * 512 + tid;            // 0..2047
        int r  = ci >> 3;                  // LDS row 0..255
        int gc = (ci & 7) ^ (r & 7);       // swizzled global chunk
        int s  = slotLds[r];
        srcA[i] = hsb + (long)(s >= 0 ? (s >> 1) : 0) * Hdim + gc * 8;
        long frow = (r < 128) ? (long)(f0 + r) : (long)(Fdim + f0 + (r - 128));
        srcB[i] = w1b + ((long)e * 2 * Fdim + frow) * Hdim + gc * 8;
    }

    const int lane = tid & 63;
    const int w = tid >> 6;              // 0..7
    const int wm = (w >> 1) * 64;        // slot-row base: 0/64/128/192
    const int fn = (w & 1) * 64;         // f-col base within 128: 0/64
    const int fr = lane & 15, fg = lane >> 4;
    const int cs0 = (fg ^ (fr & 7)) * 8;          // kk=0 chunk byte-swz (elems)
    const int cs1 = ((4 + fg) ^ (fr & 7)) * 8;    // kk=1

    floatx4 accg[4][4] = {};
    floatx4 accu[4][4] = {};

    // prologue: issue K-tile 0 stage into buffer 0 (drained by loop's t=0 wait)
#pragma unroll
    for (int i = 0; i < 4; ++i) {
        gld16(srcA[i], &As[0][(i * 512 + tid) * 8]);
        gld16(srcB[i], &Bs[0][(i * 512 + tid) * 8]);
    }

    const int NT = Hdim / 64;            // 16 K-tiles
    for (int t = 0; t < NT; ++t) {
        short* Ac = As[t & 1];
        short* Bc = Bs[t & 1];
        short* An = As[(t & 1) ^ 1];
        short* Bn = Bs[(t & 1) ^ 1];
        const bool pf = (t + 1 < NT);
        const long k1 = (long)(t + 1) * 64;

        // B1: all waves finished READING An/Bn (they were tile t-1's read bufs)
        __builtin_amdgcn_sched_barrier(0);
        __builtin_amdgcn_s_barrier();
        if (pf) {
#pragma unroll
            for (int i = 0; i < 4; ++i) {
                gld16(srcA[i] + k1, &An[(i * 512 + tid) * 8]);
                gld16(srcB[i] + k1, &Bn[(i * 512 + tid) * 8]);
            }
            // own tile-t loads (issued last iter) landed; t+1's 8 stay in flight
            asm volatile("s_waitcnt vmcnt(8)" ::: "memory");
        } else {
            asm volatile("s_waitcnt vmcnt(0)" ::: "memory");
        }
        __builtin_amdgcn_sched_barrier(0);
        // B2: everyone's tile-t slices landed
        __builtin_amdgcn_s_barrier();
        __builtin_amdgcn_sched_barrier(0);

        // barrier-free compute region: waves drift, LDS reads overlap MFMA
        bf16x8 a[4], b[4];
#pragma unroll
        for (int kk = 0; kk < 2; ++kk) {
            const int cs = kk ? cs1 : cs0;
#pragma unroll
            for (int ms = 0; ms < 4; ++ms)
                a[ms] = *(const bf16x8*)&Ac[(wm + ms * 16 + fr) * 64 + cs];
#pragma unroll
            for (int ns = 0; ns < 4; ++ns)
                b[ns] = *(const bf16x8*)&Bc[(fn + ns * 16 + fr) * 64 + cs];
            __builtin_amdgcn_s_setprio(1);
#pragma unroll
            for (int ms = 0; ms < 4; ++ms)
#pragma unroll
                for (int ns = 0; ns < 4; ++ns)
                    accg[ms][ns] = __builtin_amdgcn_mfma_f32_16x16x32_bf16(a[ms], b[ns], accg[ms][ns], 0, 0, 0);
            __builtin_amdgcn_s_setprio(0);
#pragma unroll
            for (int ns = 0; ns < 4; ++ns)
                b[ns] = *(const bf16x8*)&Bc[(128 + fn + ns * 16 + fr) * 64 + cs];
            __builtin_amdgcn_s_setprio(1);
#pragma unroll
            for (int ms = 0; ms < 4; ++ms)
#pragma unroll
                for (int ns = 0; ns < 4; ++ns)
                    accu[ms][ns] = __builtin_amdgcn_mfma_f32_16x16x32_bf16(a[ms], b[ns], accu[ms][ns], 0, 0, 0);
            __builtin_amdgcn_s_setprio(0);
        }
    }

#pragma unroll
    for (int ms = 0; ms < 4; ++ms)
#pragma unroll
        for (int ns = 0; ns < 4; ++ns)
#pragma unroll
            for (int j = 0; j < 4; ++j) {
                int m = wm + ms * 16 + fg * 4 + j;
                int slot = slotLds[m];
                if (slot >= 0) {
                    int fcol = f0 + fn + ns * 16 + fr;
                    float gv = accg[ms][ns][j];
                    float uv = accu[ms][ns][j];
                    float av = (gv / (1.f + __expf(-gv))) * uv;
                    actb[(long)slot * Fdim + fcol] = f2bf(av);
                }
            }
}

// ---------------------------------------------------------------------------
// K3: gather-GEMM2. 256 slots x 128 h, 512 threads = 8 waves (4m x 2n),
// BK=64, 32 K-tiles, double-buffered LDS (96 KB), 2-barrier drift loop with
// counted vmcnt(6). Epilogue: atomicAdd wt*y into out[token, h].
__global__ __launch_bounds__(512) void gemm2_kernel(
    const ushort_t* __restrict__ actb, const ushort_t* __restrict__ w2b,
    const int* __restrict__ counts, const int* __restrict__ tok_slot,
    const float* __restrict__ tok_wt, float* __restrict__ out)
{
    const int e = blockIdx.z;
    const int cnt = counts[e];
    const int row0 = blockIdx.y * 256;
    if (row0 >= cnt) return;
    const int h0 = blockIdx.x * 128;

    __shared__ short As[2][256 * 64];    // 2 x 32 KB
    __shared__ short Bs[2][128 * 64];    // 2 x 16 KB
    __shared__ int   slotLds[256];
    __shared__ float wtLds[256];

    const int tid = threadIdx.x;
    if (tid < 256) {
        int idx = row0 + tid;
        bool ok = idx < cnt;
        slotLds[tid] = ok ? tok_slot[e * T + idx] : -1;
        wtLds[tid]   = ok ? tok_wt [e * T + idx] : 0.f;
    }
    __syncthreads();

    // staging pointers: 4 A-chunks (2048) + 2 B-chunks (1024) per thread
    const ushort_t* srcA[4];
    const ushort_t* srcB[2];
#pragma unroll
    for (int i = 0; i < 4; ++i) {
        int ci = i * 512 + tid;            // 0..2047
        int r  = ci >> 3;                  // A row 0..255
        int gc = (ci & 7) ^ (r & 7);
        int s  = slotLds[r];
        srcA[i] = actb + (long)(s >= 0 ? s : 0) * Fdim + gc * 8;
    }
#pragma unroll
    for (int i = 0; i < 2; ++i) {
        int ci = i * 512 + tid;            // 0..1023
        int r  = ci >> 3;                  // B row 0..127
        int gc = (ci & 7) ^ (r & 7);
        srcB[i] = w2b + ((long)e * Hdim + (h0 + r)) * Fdim + gc * 8;
    }

    const int lane = tid & 63;
    const int w = tid >> 6;              // 0..7
    const int wm = (w >> 1) * 64;        // slot base: 0/64/128/192
    const int wn = (w & 1) * 64;         // h base within 128: 0/64
    const int fr = lane & 15, fg = lane >> 4;
    const int cs0 = (fg ^ (fr & 7)) * 8;
    const int cs1 = ((4 + fg) ^ (fr & 7)) * 8;

    floatx4 acc[4][4] = {};

    // prologue: issue K-tile 0 stage into buffer 0
#pragma unroll
    for (int i = 0; i < 4; ++i) gld16(srcA[i], &As[0][(i * 512 + tid) * 8]);
#pragma unroll
    for (int i = 0; i < 2; ++i) gld16(srcB[i], &Bs[0][(i * 512 + tid) * 8]);

    const int NT = Fdim / 64;            // 32 K-tiles
    for (int t = 0; t < NT; ++t) {
        short* Ac = As[t & 1];
        short* Bc = Bs[t & 1];
        short* An = As[(t & 1) ^ 1];
        short* Bn = Bs[(t & 1) ^ 1];
        const bool pf = (t + 1 < NT);
        const long k1 = (long)(t + 1) * 64;

        __builtin_amdgcn_sched_barrier(0);
        __builtin_amdgcn_s_barrier();          // B1
        if (pf) {
#pragma unroll
            for (int i = 0; i < 4; ++i) gld16(srcA[i] + k1, &An[(i * 512 + tid) * 8]);
#pragma unroll
            for (int i = 0; i < 2; ++i) gld16(srcB[i] + k1, &Bn[(i * 512 + tid) * 8]);
            asm volatile("s_waitcnt vmcnt(6)" ::: "memory");
        } else {
            asm volatile("s_waitcnt vmcnt(0)" ::: "memory");
        }
        __builtin_amdgcn_sched_barrier(0);
        __builtin_amdgcn_s_barrier();          // B2
        __builtin_amdgcn_sched_barrier(0);

        bf16x8 a[4], b[4];
#pragma unroll
        for (int kk = 0; kk < 2; ++kk) {
            const int cs = kk ? cs1 : cs0;
#pragma unroll
            for (int ms = 0; ms < 4; ++ms)
                a[ms] = *(const bf16x8*)&Ac[(wm + ms * 16 + fr) * 64 + cs];
#pragma unroll
            for (int ns = 0; ns < 4; ++ns)
                b[ns] = *(const bf16x8*)&Bc[(wn + ns * 16 + fr) * 64 + cs];
            __builtin_amdgcn_s_setprio(1);
#pragma unroll
            for (int ms = 0; ms < 4; ++ms)
#pragma unroll
                for (int ns = 0; ns < 4; ++ns)
                    acc[ms][ns] = __builtin_amdgcn_mfma_f32_16x16x32_bf16(a[ms], b[ns], acc[ms][ns], 0, 0, 0);
            __builtin_amdgcn_s_setprio(0);
        }
    }

#pragma unroll
    for (int ms = 0; ms < 4; ++ms)
#pragma unroll
        for (int ns = 0; ns < 4; ++ns)
#pragma unroll
            for (int j = 0; j < 4; ++j) {
                int m = wm + ms * 16 + fg * 4 + j;
                int slot = slotLds[m];
                if (slot >= 0) {
                    int hcol = h0 + wn + ns * 16 + fr;
                    atomicAdd(&out[(long)(slot >> 1) * Hdim + hcol],
                              acc[ms][ns][j] * wtLds[m]);
                }
            }
}

// ---------------------------------------------------------------------------
extern "C" void kernel_launch(void* const* d_in, const int* in_sizes, int n_in,
                              void* d_out, int out_size, void* d_ws, size_t ws_size,
                              hipStream_t stream)
{
    const float* hs = (const float*)d_in[0];   // [T, H] fp32
    const float* gw = (const float*)d_in[1];   // [E, H] fp32
    const float* w1 = (const float*)d_in[2];   // [E, 2F, H] fp32
    const float* w2 = (const float*)d_in[3];   // [E, H, F] fp32

    float* out        = (float*)d_out;          // [T*H] final hidden (fp32)
    float* logits_out = out + (long)T * Hdim;   // [T*E] router logits (fp32)

    // workspace (~104.3 MB): w1region recycled after gemm1 (lower 32 MB = w2b).
    // choice/cwt alias actb's head (dead before gemm1). No partial buffer.
    char* ws = (char*)d_ws;
    size_t off = 0;
    int* counts = (int*)(ws + off);          off += 256;
    int* tok_slot = (int*)(ws + off);        off += (size_t)NE * T * sizeof(int);
    float* tok_wt = (float*)(ws + off);      off += (size_t)NE * T * sizeof(float);
    off = (off + 255) & ~(size_t)255;
    ushort_t* hsb = (ushort_t*)(ws + off);   off += (size_t)T * Hdim * sizeof(ushort_t);   // 8 MB
    off = (off + 255) & ~(size_t)255;
    char* w1region = ws + off;               off += (size_t)NE * 2 * Fdim * Hdim * sizeof(ushort_t); // 64 MB
    ushort_t* w1b = (ushort_t*)w1region;
    ushort_t* w2b = (ushort_t*)w1region;                                     // 32 MB (lower half)
    off = (off + 255) & ~(size_t)255;
    ushort_t* actb = (ushort_t*)(ws + off);  off += (size_t)TK * Fdim * sizeof(ushort_t);  // 32 MB
    int2*   choice = (int2*)actb;                       // 32 KB  (dead before gemm1)
    float2* cwt    = (float2*)((char*)actb + (size_t)T * sizeof(int2));   // 32 KB

    const long n8_w1 = (long)NE * 2 * Fdim * Hdim / 8;        //  4194304
    const long n8_w2 = (long)NE * Hdim * Fdim / 8;            //  2097152

    cvt_kernel<<<(int)(n8_w1 / 256), 256, 0, stream>>>(w1, w1b);
    router_kernel<<<T, 64, 0, stream>>>(hs, gw, logits_out, out, hsb, choice, cwt, counts);
    scatter_kernel<<<T / 256, 256, 0, stream>>>(choice, cwt, counts, tok_slot, tok_wt);
    gemm1_kernel<<<dim3(Fdim / 128, T / 256, NE), 512, 0, stream>>>(hsb, w1b, counts, tok_slot, actb);
    cvt_kernel<<<(int)(n8_w2 / 256), 256, 0, stream>>>(w2, w2b);   // into recycled w1b (lower half)
    gemm2_kernel<<<dim3(Hdim / 128, T / 256, NE), 512, 0, stream>>>(actb, w2b, counts, tok_slot, tok_wt, out);
}

// Round 7
// 437.643 us; speedup vs baseline: 1.0948x; 1.0948x over previous
//
#include <hip/hip_runtime.h>

// TBStars2 MoE sparse block — fp32 I/O, bf16 MFMA compute
// R15: gemm1 gets a one-group-deep FRAGMENT pipeline (m201 discipline):
// each phase reads the NEXT MFMA group's LDS fragments BEFORE the barrier,
// counted lgkmcnt (4/8/4/0, 12 reads always in flight) so ds_read and MFMA
// overlap across waves; staging split A@P0 / B@P1 with vmcnt(0)+barrier only
// at P3 (3 phases of cover); next tile's first group read at P3 from the
// other buffer. 4 barriers/tile. gemm2 / router / scatter / cvt = R13 form
// (gemm2 atomicAdds into out; router zeroes out rows; no combine kernel).
#define T 4096
#define Hdim 1024
#define Fdim 2048
#define NE 8
#define TOPK 2
#define TK (T*TOPK)

typedef unsigned short ushort_t;
typedef __attribute__((ext_vector_type(8))) short bf16x8;   // 8 x bf16 (4 VGPRs)
typedef __attribute__((ext_vector_type(4))) float floatx4;  // mfma accumulator

__device__ __forceinline__ ushort_t f2bf(float f) {
    unsigned u = __float_as_uint(f);
    u += 0x7fff + ((u >> 16) & 1);   // RNE
    return (ushort_t)(u >> 16);
}
__device__ __forceinline__ uint4 cvt8(const float4 a, const float4 b) {
    uint4 r;
    r.x = (unsigned)f2bf(a.x) | ((unsigned)f2bf(a.y) << 16);
    r.y = (unsigned)f2bf(a.z) | ((unsigned)f2bf(a.w) << 16);
    r.z = (unsigned)f2bf(b.x) | ((unsigned)f2bf(b.y) << 16);
    r.w = (unsigned)f2bf(b.z) | ((unsigned)f2bf(b.w) << 16);
    return r;
}
// async 16B global->LDS (per-lane gather src; LDS dest = wave base + lane*16)
__device__ __forceinline__ void gld16(const ushort_t* g, short* l) {
    __builtin_amdgcn_global_load_lds((const __attribute__((address_space(1))) void*)g,
                                     (__attribute__((address_space(3))) void*)l, 16, 0, 0);
}

// ---------------------------------------------------------------------------
// K0: fp32 -> bf16 convert, exact grid, 8 elems/thread
__global__ __launch_bounds__(256) void cvt_kernel(const float* __restrict__ src,
                                                  ushort_t* __restrict__ dst)
{
    long i = (long)blockIdx.x * 256 + threadIdx.x;
    float4 a = *(const float4*)(src + i * 8);
    float4 b = *(const float4*)(src + i * 8 + 4);
    *(uint4*)(dst + i * 8) = cvt8(a, b);
}

// ---------------------------------------------------------------------------
// K1: router. One wave per token, fp32. Also converts its hs row -> hsb (bf16),
// zeroes its out row (gemm2 accumulates into it atomically), and (block 0)
// zeroes counts.
__global__ __launch_bounds__(64) void router_kernel(
    const float* __restrict__ hs, const float* __restrict__ gw,
    float* __restrict__ logits_out, float* __restrict__ out,
    ushort_t* __restrict__ hsb,
    int2* __restrict__ choice, float2* __restrict__ cwt, int* __restrict__ counts)
{
    const int t = blockIdx.x;
    const int lane = threadIdx.x;
    if (t == 0 && lane < NE) counts[lane] = 0;

    float hreg[16];
#pragma unroll
    for (int i = 0; i < 16; ++i)
        hreg[i] = hs[(long)t * Hdim + lane + 64 * i];

#pragma unroll
    for (int i = 0; i < 16; ++i)
        hsb[(long)t * Hdim + lane + 64 * i] = f2bf(hreg[i]);

    // zero this token's output row (accumulated by gemm2 atomics)
    const float4 z4 = make_float4(0.f, 0.f, 0.f, 0.f);
#pragma unroll
    for (int i = 0; i < 4; ++i)
        *(float4*)&out[(long)t * Hdim + lane * 4 + 256 * i] = z4;

    float acc[NE];
#pragma unroll
    for (int e = 0; e < NE; ++e) {
        float s = 0.f;
#pragma unroll
        for (int i = 0; i < 16; ++i)
            s += hreg[i] * gw[e * Hdim + lane + 64 * i];
#pragma unroll
        for (int off = 32; off > 0; off >>= 1)
            s += __shfl_xor(s, off, 64);
        acc[e] = s;
    }

    if (lane < NE) logits_out[t * NE + lane] = acc[lane];

    if (lane == 0) {
        int i1 = 0;
#pragma unroll
        for (int e = 1; e < NE; ++e) if (acc[e] > acc[i1]) i1 = e;
        int i2 = -1;
#pragma unroll
        for (int e = 0; e < NE; ++e) {
            if (e == i1) continue;
            if (i2 < 0 || acc[e] > acc[i2]) i2 = e;
        }
        float p2 = __expf(acc[i2] - acc[i1]);
        float z  = 1.f + p2;
        choice[t] = make_int2(i1, i2);
        cwt[t]    = make_float2(1.f / z, p2 / z);
    }
}

// K1b: scatter. Block = 256 tokens. LDS histogram -> 8 global atomics/block.
__global__ __launch_bounds__(256) void scatter_kernel(
    const int2* __restrict__ choice, const float2* __restrict__ cwt,
    int* __restrict__ counts, int* __restrict__ tok_slot, float* __restrict__ tok_wt)
{
    __shared__ int lhist[NE];
    __shared__ int lbase[NE];
    __shared__ int lpos[NE];
    const int tid = threadIdx.x;
    if (tid < NE) { lhist[tid] = 0; lpos[tid] = 0; }
    __syncthreads();

    const int t = blockIdx.x * 256 + tid;
    int2   ch = choice[t];
    float2 wv = cwt[t];
    atomicAdd(&lhist[ch.x], 1);
    atomicAdd(&lhist[ch.y], 1);
    __syncthreads();

    if (tid < NE) lbase[tid] = atomicAdd(&counts[tid], lhist[tid]);
    __syncthreads();

    int p1 = atomicAdd(&lpos[ch.x], 1);   // ch.x != ch.y
    int p2 = atomicAdd(&lpos[ch.y], 1);
    int o1 = lbase[ch.x] + p1;
    int o2 = lbase[ch.y] + p2;
    tok_slot[ch.x * T + o1] = t * TOPK + 0;
    tok_wt [ch.x * T + o1] = wv.x;
    tok_slot[ch.y * T + o2] = t * TOPK + 1;
    tok_wt [ch.y * T + o2] = wv.y;
}

// ---------------------------------------------------------------------------
// K2: gather-GEMM1 + SwiGLU. 256 slots x 128 f (B rows: 128 gate + 128 up),
// 512 threads = 8 waves (4m x 2fn), BK=64, 16 K-tiles, double-buffered LDS
// (128 KB). 4-phase fragment-pipelined K-loop (see header comment).
// Groups: G0={a cs0, bg cs0}(8) G1={bu cs0}(4) G2={a cs1, bg cs1}(8)
//         G3={bu cs1}(4); MFMA M0..M3 each 16x mfma_16x16x32.
__global__ __launch_bounds__(512) void gemm1_kernel(
    const ushort_t* __restrict__ hsb, const ushort_t* __restrict__ w1b,
    const int* __restrict__ counts, const int* __restrict__ tok_slot,
    ushort_t* __restrict__ actb)
{
    const int e = blockIdx.z;
    const int cnt = counts[e];
    const int row0 = blockIdx.y * 256;
    if (row0 >= cnt) return;
    const int f0 = blockIdx.x * 128;

    __shared__ short As[2][256 * 64];    // 2 x 32 KB
    __shared__ short Bs[2][256 * 64];    // 2 x 32 KB: rows 0-127 gate, 128-255 up
    __shared__ int slotLds[256];

    const int tid = threadIdx.x;
    if (tid < 256) {
        int idx = row0 + tid;
        slotLds[tid] = (idx < cnt) ? tok_slot[e * T + idx] : -1;
    }
    __syncthreads();

    // staging pointers: 4 A-chunks + 4 B-chunks per thread (2048 chunks each)
    const ushort_t* srcA[4];
    const ushort_t* srcB[4];
#pragma unroll
    for (int i = 0; i < 4; ++i) {
        int ci = i * 512 + tid;            // 0..2047
        int r  = ci >> 3;                  // LDS row 0..255
        int gc = (ci & 7) ^ (r & 7);       // swizzled global chunk
        int s  = slotLds[r];
        srcA[i] = hsb + (long)(s >= 0 ? (s >> 1) : 0) * Hdim + gc * 8;
        long frow = (r < 128) ? (long)(f0 + r) : (long)(Fdim + f0 + (r - 128));
        srcB[i] = w1b + ((long)e * 2 * Fdim + frow) * Hdim + gc * 8;
    }

    const int lane = tid & 63;
    const int w = tid >> 6;              // 0..7
    const int wm = (w >> 1) * 64;        // slot-row base: 0/64/128/192
    const int fn = (w & 1) * 64;         // f-col base within 128: 0/64
    const int fr = lane & 15, fg = lane >> 4;
    const int cs0 = (fg ^ (fr & 7)) * 8;          // kk=0 chunk byte-swz (elems)
    const int cs1 = ((4 + fg) ^ (fr & 7)) * 8;    // kk=1

    floatx4 accg[4][4] = {};
    floatx4 accu[4][4] = {};
    bf16x8 a0[4], a1[4], bg[4], bu[4];

    // prologue: stage tile 0, drain, read G0 (leave its 8 reads pending)
#pragma unroll
    for (int i = 0; i < 4; ++i) {
        gld16(srcA[i], &As[0][(i * 512 + tid) * 8]);
        gld16(srcB[i], &Bs[0][(i * 512 + tid) * 8]);
    }
    asm volatile("s_waitcnt vmcnt(0)" ::: "memory");
    __builtin_amdgcn_s_barrier();
    __builtin_amdgcn_sched_barrier(0);
#pragma unroll
    for (int ms = 0; ms < 4; ++ms)
        a0[ms] = *(const bf16x8*)&As[0][(wm + ms * 16 + fr) * 64 + cs0];
#pragma unroll
    for (int ns = 0; ns < 4; ++ns)
        bg[ns] = *(const bf16x8*)&Bs[0][(fn + ns * 16 + fr) * 64 + cs0];
    __builtin_amdgcn_sched_barrier(0);

    const int NT = Hdim / 64;            // 16 K-tiles
    for (int t = 0; t < NT; ++t) {
        const short* Ac = As[t & 1];
        const short* Bc = Bs[t & 1];
        short* An = As[(t & 1) ^ 1];
        short* Bn = Bs[(t & 1) ^ 1];
        const bool pf = (t + 1 < NT);
        const long k1 = (long)(t + 1) * 64;

        // ---- P0: stage A(t+1); read G1(bu cs0); M0 = accg += a0*bg ----
        if (pf) {
#pragma unroll
            for (int i = 0; i < 4; ++i)
                gld16(srcA[i] + k1, &An[(i * 512 + tid) * 8]);
        }
#pragma unroll
        for (int ns = 0; ns < 4; ++ns)
            bu[ns] = *(const bf16x8*)&Bc[(128 + fn + ns * 16 + fr) * 64 + cs0];
        __builtin_amdgcn_sched_barrier(0);
        __builtin_amdgcn_s_barrier();
        asm volatile("s_waitcnt lgkmcnt(4)" ::: "memory");   // G0 done, G1 fly
        __builtin_amdgcn_sched_barrier(0);
        __builtin_amdgcn_s_setprio(1);
#pragma unroll
        for (int ms = 0; ms < 4; ++ms)
#pragma unroll
            for (int ns = 0; ns < 4; ++ns)
                accg[ms][ns] = __builtin_amdgcn_mfma_f32_16x16x32_bf16(a0[ms], bg[ns], accg[ms][ns], 0, 0, 0);
        __builtin_amdgcn_s_setprio(0);

        // ---- P1: stage B(t+1); read G2(a1,bg cs1); M1 = accu += a0*bu --
        if (pf) {
#pragma unroll
            for (int i = 0; i < 4; ++i)
                gld16(srcB[i] + k1, &Bn[(i * 512 + tid) * 8]);
        }
#pragma unroll
        for (int ms = 0; ms < 4; ++ms)
            a1[ms] = *(const bf16x8*)&Ac[(wm + ms * 16 + fr) * 64 + cs1];
#pragma unroll
        for (int ns = 0; ns < 4; ++ns)
            bg[ns] = *(const bf16x8*)&Bc[(fn + ns * 16 + fr) * 64 + cs1];
        __builtin_amdgcn_sched_barrier(0);
        __builtin_amdgcn_s_barrier();
        asm volatile("s_waitcnt lgkmcnt(8)" ::: "memory");   // G1 done, G2 fly
        __builtin_amdgcn_sched_barrier(0);
        __builtin_amdgcn_s_setprio(1);
#pragma unroll
        for (int ms = 0; ms < 4; ++ms)
#pragma unroll
            for (int ns = 0; ns < 4; ++ns)
                accu[ms][ns] = __builtin_amdgcn_mfma_f32_16x16x32_bf16(a0[ms], bu[ns], accu[ms][ns], 0, 0, 0);
        __builtin_amdgcn_s_setprio(0);

        // ---- P2: read G3(bu cs1); M2 = accg += a1*bg -------------------
#pragma unroll
        for (int ns = 0; ns < 4; ++ns)
            bu[ns] = *(const bf16x8*)&Bc[(128 + fn + ns * 16 + fr) * 64 + cs1];
        __builtin_amdgcn_sched_barrier(0);
        __builtin_amdgcn_s_barrier();
        asm volatile("s_waitcnt lgkmcnt(4)" ::: "memory");   // G2 done, G3 fly
        __builtin_amdgcn_sched_barrier(0);
        __builtin_amdgcn_s_setprio(1);
#pragma unroll
        for (int ms = 0; ms < 4; ++ms)
#pragma unroll
            for (int ns = 0; ns < 4; ++ns)
                accg[ms][ns] = __builtin_amdgcn_mfma_f32_16x16x32_bf16(a1[ms], bg[ns], accg[ms][ns], 0, 0, 0);
        __builtin_amdgcn_s_setprio(0);

        // ---- P3: drain G3 + staging; publish; read G0'(t+1); M3 --------
        __builtin_amdgcn_sched_barrier(0);
        asm volatile("s_waitcnt vmcnt(0) lgkmcnt(0)" ::: "memory");
        __builtin_amdgcn_s_barrier();
        __builtin_amdgcn_sched_barrier(0);
        if (pf) {
#pragma unroll
            for (int ms = 0; ms < 4; ++ms)
                a0[ms] = *(const bf16x8*)&An[(wm + ms * 16 + fr) * 64 + cs0];
#pragma unroll
            for (int ns = 0; ns < 4; ++ns)
                bg[ns] = *(const bf16x8*)&Bn[(fn + ns * 16 + fr) * 64 + cs0];
        }
        __builtin_amdgcn_sched_barrier(0);
        __builtin_amdgcn_s_setprio(1);
#pragma unroll
        for (int ms = 0; ms < 4; ++ms)
#pragma unroll
            for (int ns = 0; ns < 4; ++ns)
                accu[ms][ns] = __builtin_amdgcn_mfma_f32_16x16x32_bf16(a1[ms], bu[ns], accu[ms][ns], 0, 0, 0);
        __builtin_amdgcn_s_setprio(0);
    }

#pragma unroll
    for (int ms = 0; ms < 4; ++ms)
#pragma unroll
        for (int ns = 0; ns < 4; ++ns)
#pragma unroll
            for (int j = 0; j < 4; ++j) {
                int m = wm + ms * 16 + fg * 4 + j;
                int slot = slotLds[m];
                if (slot >= 0) {
                    int fcol = f0 + fn + ns * 16 + fr;
                    float gv = accg[ms][ns][j];
                    float uv = accu[ms][ns][j];
                    float av = (gv / (1.f + __expf(-gv))) * uv;
                    actb[(long)slot * Fdim + fcol] = f2bf(av);
                }
            }
}

// ---------------------------------------------------------------------------
// K3: gather-GEMM2, 128x128 tile, 512 threads (8 waves, 2x4), BK=64, 32 steps
// (R13 form). Epilogue: atomicAdd wt*y directly into out[token, h].
__global__ __launch_bounds__(512) void gemm2_kernel(
    const ushort_t* __restrict__ actb, const ushort_t* __restrict__ w2b,
    const int* __restrict__ counts, const int* __restrict__ tok_slot,
    const float* __restrict__ tok_wt, float* __restrict__ out)
{
    const int e = blockIdx.z;
    const int cnt = counts[e];
    const int row0 = blockIdx.y * 128;
    if (row0 >= cnt) return;
    const int h0 = blockIdx.x * 128;

    __shared__ short As[128 * 64];
    __shared__ short Bs[128 * 64];
    __shared__ int   slotLds[128];
    __shared__ float wtLds[128];

    const int tid = threadIdx.x;
    if (tid < 128) {
        int idx = row0 + tid;
        bool ok = idx < cnt;
        slotLds[tid] = ok ? tok_slot[e * T + idx] : -1;
        wtLds[tid]   = ok ? tok_wt [e * T + idx] : 0.f;
    }
    __syncthreads();

    const ushort_t* srcA[2];
    const ushort_t* srcB[2];
#pragma unroll
    for (int i = 0; i < 2; ++i) {
        int ci = i * 512 + tid;            // 0..1023
        int r  = ci >> 3;
        int gc = (ci & 7) ^ (r & 7);
        int s  = slotLds[r];
        srcA[i] = actb + (long)(s >= 0 ? s : 0) * Fdim + gc * 8;
        srcB[i] = w2b + ((long)e * Hdim + (h0 + r)) * Fdim + gc * 8;
    }

    const int lane = tid & 63;
    const int w = tid >> 6;              // 0..7
    const int wm = (w >> 2) * 64;
    const int wn = (w & 3) * 32;
    const int fr = lane & 15, fg = lane >> 4;
    const int cs0 = (fg ^ (fr & 7)) * 8;
    const int cs1 = ((4 + fg) ^ (fr & 7)) * 8;

    floatx4 acc[4][2] = {};

    for (int k0 = 0; k0 < Fdim; k0 += 64) {
        __syncthreads();
        gld16(srcA[0] + k0, &As[tid * 8]);
        gld16(srcA[1] + k0, &As[(512 + tid) * 8]);
        gld16(srcB[0] + k0, &Bs[tid * 8]);
        gld16(srcB[1] + k0, &Bs[(512 + tid) * 8]);
        __syncthreads();

#pragma unroll
        for (int kk = 0; kk < 2; ++kk) {
            const int cs = kk ? cs1 : cs0;
            bf16x8 a[4], b[2];
#pragma unroll
            for (int ms = 0; ms < 4; ++ms)
                a[ms] = *(bf16x8*)&As[(wm + ms * 16 + fr) * 64 + cs];
#pragma unroll
            for (int ns = 0; ns < 2; ++ns)
                b[ns] = *(bf16x8*)&Bs[(wn + ns * 16 + fr) * 64 + cs];
#pragma unroll
            for (int ms = 0; ms < 4; ++ms)
#pragma unroll
                for (int ns = 0; ns < 2; ++ns)
                    acc[ms][ns] = __builtin_amdgcn_mfma_f32_16x16x32_bf16(a[ms], b[ns], acc[ms][ns], 0, 0, 0);
        }
    }

#pragma unroll
    for (int ms = 0; ms < 4; ++ms)
#pragma unroll
        for (int ns = 0; ns < 2; ++ns)
#pragma unroll
            for (int j = 0; j < 4; ++j) {
                int m = wm + ms * 16 + fg * 4 + j;
                int slot = slotLds[m];
                if (slot >= 0) {
                    int hcol = h0 + wn + ns * 16 + fr;
                    atomicAdd(&out[(long)(slot >> 1) * Hdim + hcol],
                              acc[ms][ns][j] * wtLds[m]);
                }
            }
}

// ---------------------------------------------------------------------------
extern "C" void kernel_launch(void* const* d_in, const int* in_sizes, int n_in,
                              void* d_out, int out_size, void* d_ws, size_t ws_size,
                              hipStream_t stream)
{
    const float* hs = (const float*)d_in[0];   // [T, H] fp32
    const float* gw = (const float*)d_in[1];   // [E, H] fp32
    const float* w1 = (const float*)d_in[2];   // [E, 2F, H] fp32
    const float* w2 = (const float*)d_in[3];   // [E, H, F] fp32

    float* out        = (float*)d_out;          // [T*H] final hidden (fp32)
    float* logits_out = out + (long)T * Hdim;   // [T*E] router logits (fp32)

    // workspace (~104.3 MB): w1region recycled after gemm1 (lower 32 MB = w2b).
    // choice/cwt alias actb's head (dead before gemm1). No partial buffer.
    char* ws = (char*)d_ws;
    size_t off = 0;
    int* counts = (int*)(ws + off);          off += 256;
    int* tok_slot = (int*)(ws + off);        off += (size_t)NE * T * sizeof(int);
    float* tok_wt = (float*)(ws + off);      off += (size_t)NE * T * sizeof(float);
    off = (off + 255) & ~(size_t)255;
    ushort_t* hsb = (ushort_t*)(ws + off);   off += (size_t)T * Hdim * sizeof(ushort_t);   // 8 MB
    off = (off + 255) & ~(size_t)255;
    char* w1region = ws + off;               off += (size_t)NE * 2 * Fdim * Hdim * sizeof(ushort_t); // 64 MB
    ushort_t* w1b = (ushort_t*)w1region;
    ushort_t* w2b = (ushort_t*)w1region;                                     // 32 MB (lower half)
    off = (off + 255) & ~(size_t)255;
    ushort_t* actb = (ushort_t*)(ws + off);  off += (size_t)TK * Fdim * sizeof(ushort_t);  // 32 MB
    int2*   choice = (int2*)actb;                       // 32 KB  (dead before gemm1)
    float2* cwt    = (float2*)((char*)actb + (size_t)T * sizeof(int2));   // 32 KB

    const long n8_w1 = (long)NE * 2 * Fdim * Hdim / 8;        //  4194304
    const long n8_w2 = (long)NE * Hdim * Fdim / 8;            //  2097152

    cvt_kernel<<<(int)(n8_w1 / 256), 256, 0, stream>>>(w1, w1b);
    router_kernel<<<T, 64, 0, stream>>>(hs, gw, logits_out, out, hsb, choice, cwt, counts);
    scatter_kernel<<<T / 256, 256, 0, stream>>>(choice, cwt, counts, tok_slot, tok_wt);
    gemm1_kernel<<<dim3(Fdim / 128, T / 256, NE), 512, 0, stream>>>(hsb, w1b, counts, tok_slot, actb);
    cvt_kernel<<<(int)(n8_w2 / 256), 256, 0, stream>>>(w2, w2b);   // into recycled w1b (lower half)
    gemm2_kernel<<<dim3(Hdim / 128, T / 128, NE), 512, 0, stream>>>(actb, w2b, counts, tok_slot, tok_wt, out);
}